// Round 7
// baseline (61.391 us; speedup 1.0000x reference)
//
#include <hip/hip_runtime.h>

#define N_AB  1024
#define NHALF 1025
#define NFULL 2049
#define HDIM  64
#define PLANE ((size_t)N_AB * NFULL)
#define C2L   2.8853900817779268f   // 2*log2(e)

typedef __bf16 bf16x8 __attribute__((ext_vector_type(8)));
typedef __bf16 bf16x4 __attribute__((ext_vector_type(4)));
typedef float  f32x4  __attribute__((ext_vector_type(4)));
typedef float  f32x2  __attribute__((ext_vector_type(2)));

#define MFMA16(A,B,C) __builtin_amdgcn_mfma_f32_16x16x32_bf16(A,B,C,0,0,0)

// Packed (float2) tanh core: S2 = z*2log2e (pair). H2 = tanh(z), T2 = u-u^2 (1-H^2 = 4T).
// Regular ops are f32x2 -> v_pk_* VOP3P; exp2/rcp stay scalar (no packed transcendentals).
#define ACT2(S2,H2,T2) { \
    f32x2 _e; _e.x = __builtin_amdgcn_exp2f(S2.x); _e.y = __builtin_amdgcn_exp2f(S2.y); \
    f32x2 _d = _e + 1.0f; \
    f32x2 _u; _u.x = __builtin_amdgcn_rcpf(_d.x); _u.y = __builtin_amdgcn_rcpf(_d.y); \
    H2 = __builtin_elementwise_fma(_km2, _u, _k1); \
    T2 = __builtin_elementwise_fma(-_u, _u, _u); }

// layer-1 element pair: WC2 = w0*C2L, BC2 = b0*C2L, W42 = w0*4 ; h -> BV, 4t*w0 -> BT
#define L1P(I0, WC2, BC2, W42, BV, BT) { \
    f32x2 _s = __builtin_elementwise_fma(WC2, x2, BC2); \
    f32x2 _h, _t; ACT2(_s,_h,_t) \
    f32x2 _bt = _t * W42; \
    BV[I0] = (__bf16)_h.x; BV[I0+1] = (__bf16)_h.y; \
    BT[I0] = (__bf16)_bt.x; BT[I0+1] = (__bf16)_bt.y; }

// layer-2 element pair: AV2=z2pre, AT2=dz2pre, B1C2=b1*C2L ; accumulate L3 partial pairs.
// _dh carries t*dacc only; missing *4 folded into the 8.0f in da/db.
#define L2P(AV2, AT2, B1C2, W20_2, W21_2) { \
    f32x2 _s = __builtin_elementwise_fma(AV2, c2l2, B1C2); \
    f32x2 _h, _t; ACT2(_s,_h,_t) \
    f32x2 _dh = _t * (AT2); \
    pv0_2 = __builtin_elementwise_fma(W20_2, _h,  pv0_2); \
    pv1_2 = __builtin_elementwise_fma(W21_2, _h,  pv1_2); \
    pt0_2 = __builtin_elementwise_fma(W20_2, _dh, pt0_2); \
    pt1_2 = __builtin_elementwise_fma(W21_2, _dh, pt1_2); }

#define L2QUAD(AV,AT,B1,WR0,WR1) \
    L2P(AV.xy, AT.xy, B1.xy, WR0.xy, WR1.xy) \
    L2P(AV.zw, AT.zw, B1.zw, WR0.zw, WR1.zw)

// full per-point-tile pipeline; leaves xp,yp,xpp,ypp in scope
#define COMPUTE_TILE(XV) \
    const float x = (XV); \
    const f32x2 x2 = {x, x}; \
    const float sa = __sinf(x), ca = __cosf(x); \
    const float cam1 = ca - 1.0f; \
    bf16x8 bv0, bv1, bt0, bt1; \
    L1P(0, w0A.xy, b0A.xy, w4A.xy, bv0, bt0) \
    L1P(2, w0A.zw, b0A.zw, w4A.zw, bv0, bt0) \
    L1P(4, w0B.xy, b0B.xy, w4B.xy, bv0, bt0) \
    L1P(6, w0B.zw, b0B.zw, w4B.zw, bv0, bt0) \
    L1P(0, w0C.xy, b0C.xy, w4C.xy, bv1, bt1) \
    L1P(2, w0C.zw, b0C.zw, w4C.zw, bv1, bt1) \
    L1P(4, w0D.xy, b0D.xy, w4D.xy, bv1, bt1) \
    L1P(6, w0D.zw, b0D.zw, w4D.zw, bv1, bt1) \
    const f32x4 zz = {0.0f,0.0f,0.0f,0.0f}; \
    f32x4 av0 = MFMA16(A01,bv1,MFMA16(A00,bv0,zz)); \
    f32x4 av1 = MFMA16(A11,bv1,MFMA16(A10,bv0,zz)); \
    f32x4 av2 = MFMA16(A21,bv1,MFMA16(A20,bv0,zz)); \
    f32x4 av3 = MFMA16(A31,bv1,MFMA16(A30,bv0,zz)); \
    f32x4 at0 = MFMA16(A01,bt1,MFMA16(A00,bt0,zz)); \
    f32x4 at1 = MFMA16(A11,bt1,MFMA16(A10,bt0,zz)); \
    f32x4 at2 = MFMA16(A21,bt1,MFMA16(A20,bt0,zz)); \
    f32x4 at3 = MFMA16(A31,bt1,MFMA16(A30,bt0,zz)); \
    f32x2 pv0_2 = {0.0f,0.0f}, pv1_2 = {0.0f,0.0f}; \
    f32x2 pt0_2 = {0.0f,0.0f}, pt1_2 = {0.0f,0.0f}; \
    L2QUAD(av0,at0,b1c0,w2a0,w2b0) \
    L2QUAD(av1,at1,b1c1,w2a1,w2b1) \
    L2QUAD(av2,at2,b1c2,w2a2,w2b2) \
    L2QUAD(av3,at3,b1c3,w2a3,w2b3) \
    float pv0 = pv0_2.x + pv0_2.y, pv1 = pv1_2.x + pv1_2.y; \
    float pt0 = pt0_2.x + pt0_2.y, pt1 = pt1_2.x + pt1_2.y; \
    pv0 += __shfl_xor(pv0,16); pv0 += __shfl_xor(pv0,32); \
    pv1 += __shfl_xor(pv1,16); pv1 += __shfl_xor(pv1,32); \
    pt0 += __shfl_xor(pt0,16); pt0 += __shfl_xor(pt0,32); \
    pt1 += __shfl_xor(pt1,16); pt1 += __shfl_xor(pt1,32); \
    const float z0 = pv0 + b20, z1 = pv1 + b21; \
    const float aa = z0*z0, bb = z1*z1; \
    const float da = 8.0f*z0*pt0, db = 8.0f*z1*pt1; \
    const float xp = aa*cam1, yp = bb*sa; \
    const float xpp = fmaf(da,cam1,-(aa*sa)); \
    const float ypp = fmaf(bb,ca, db*sa);

__global__ void __launch_bounds__(256, 2) sofa_kernel(   // (256,2): proven no-spill setting
    const float* __restrict__ alpha,
    const float* __restrict__ w0,
    const float* __restrict__ w1,
    const float* __restrict__ w2,
    const float* __restrict__ b0,
    const float* __restrict__ b1,
    const float* __restrict__ b2,
    float* __restrict__ out)
{
    __shared__ __align__(16) __bf16 w1s[HDIM * HDIM];   // XOR-swizzled bf16 W1
    __shared__ float s_alpha[NHALF];
    __shared__ float s_xplast;

    const int n    = blockIdx.x;
    const int half = blockIdx.y;        // 0: points 0..511, 1: points 512..1023
    const int tid  = threadIdx.x;
    const int lane = tid & 63;
    const int wid  = tid >> 6;
    const int col  = lane & 15;   // MFMA col (point) / A-row index
    const int grp  = lane >> 4;   // k-slot group / output-plane selector

    const float* __restrict__ w0n = w0 + (size_t)n * HDIM;
    const float* __restrict__ b0n = b0 + (size_t)n * HDIM;
    const float* __restrict__ w1n = w1 + (size_t)n * HDIM * HDIM;
    const float* __restrict__ b1n = b1 + (size_t)n * HDIM;
    const float* __restrict__ w2n = w2 + (size_t)n * 2 * HDIM;
    const float* __restrict__ b2n = b2 + (size_t)n * 2;

    // ---- stage alpha (fp32) and W1 (bf16, 16B-group XOR swizzle) into LDS ----
    for (int e = tid; e < NHALF; e += 256) s_alpha[e] = alpha[e];
    for (int e4 = tid; e4 < (HDIM * HDIM) / 4; e4 += 256) {
        const int i = e4 >> 4, j4 = (e4 & 15) << 2;
        f32x4 v = ((const f32x4*)w1n)[e4];
        bf16x4 b;
        b[0] = (__bf16)v.x; b[1] = (__bf16)v.y; b[2] = (__bf16)v.z; b[3] = (__bf16)v.w;
        *(bf16x4*)&w1s[i * 64 + (((j4 >> 3) ^ (i & 7)) << 3) + (j4 & 7)] = b;
    }
    __syncthreads();

    // ---- constants for packed math ----
    const f32x2 _km2 = {-2.0f, -2.0f};
    const f32x2 _k1  = { 1.0f,  1.0f};
    const f32x2 c2l2 = { C2L,   C2L };

    // ---- per-lane hoisted constants (named ext-vectors -> SSA, no allocas) ----
    const int jb0 = grp * 8, jb1 = 32 + grp * 8;
    f32x4 w0A = *(const f32x4*)(w0n + jb0);
    f32x4 w0B = *(const f32x4*)(w0n + jb0 + 4);
    f32x4 w0C = *(const f32x4*)(w0n + jb1);
    f32x4 w0D = *(const f32x4*)(w0n + jb1 + 4);
    f32x4 w4A = w0A * 4.0f, w4B = w0B * 4.0f, w4C = w0C * 4.0f, w4D = w0D * 4.0f;
    w0A *= C2L; w0B *= C2L; w0C *= C2L; w0D *= C2L;
    f32x4 b0A = *(const f32x4*)(b0n + jb0);
    f32x4 b0B = *(const f32x4*)(b0n + jb0 + 4);
    f32x4 b0C = *(const f32x4*)(b0n + jb1);
    f32x4 b0D = *(const f32x4*)(b0n + jb1 + 4);
    b0A *= C2L; b0B *= C2L; b0C *= C2L; b0D *= C2L;

    f32x4 b1c0 = *(const f32x4*)(b1n + 0  + grp * 4);
    f32x4 b1c1 = *(const f32x4*)(b1n + 16 + grp * 4);
    f32x4 b1c2 = *(const f32x4*)(b1n + 32 + grp * 4);
    f32x4 b1c3 = *(const f32x4*)(b1n + 48 + grp * 4);
    b1c0 *= C2L; b1c1 *= C2L; b1c2 *= C2L; b1c3 *= C2L;

    const f32x4 w2a0 = *(const f32x4*)(w2n + 0  + grp * 4);
    const f32x4 w2a1 = *(const f32x4*)(w2n + 16 + grp * 4);
    const f32x4 w2a2 = *(const f32x4*)(w2n + 32 + grp * 4);
    const f32x4 w2a3 = *(const f32x4*)(w2n + 48 + grp * 4);
    const f32x4 w2b0 = *(const f32x4*)(w2n + 64 + 0  + grp * 4);
    const f32x4 w2b1 = *(const f32x4*)(w2n + 64 + 16 + grp * 4);
    const f32x4 w2b2 = *(const f32x4*)(w2n + 64 + 32 + grp * 4);
    const f32x4 w2b3 = *(const f32x4*)(w2n + 64 + 48 + grp * 4);
    const float b20 = b2n[0], b21 = b2n[1];

    // ---- A-fragments: W1 rows in registers (lane: row=col, k = 32*KH + 8*grp + 0..7) ----
    const bf16x8* w1v = (const bf16x8*)w1s;
    const int sw = col & 7;
#define AF(RT,KH) w1v[((RT)*16 + col)*8 + (((KH)*4 + grp) ^ sw)]
    const bf16x8 A00 = AF(0,0), A01 = AF(0,1), A10 = AF(1,0), A11 = AF(1,1);
    const bf16x8 A20 = AF(2,0), A21 = AF(2,1), A30 = AF(3,0), A31 = AF(3,1);

    const size_t obase = (size_t)grp * PLANE + (size_t)n * NFULL;

    // ---- point 1024 first (wave 0), to get xp_last for the xp mirror ----
    // (both half-blocks compute it; identical deterministic value, benign dup store)
    if (wid == 0) {
        COMPUTE_TILE(s_alpha[1024])
        if (col == 0) {
            out[obase + 1024] = (grp == 0) ? xp : (grp == 1) ? yp : (grp == 2) ? xpp : ypp;
            if (grp == 0) s_xplast = xp;
        }
    }
    __syncthreads();
    const float xl2 = 2.0f * s_xplast;

    // ---- main loop: 8 iters/wave, 16 points each; this block covers 512 points ----
    // rotating alpha prefetch: next tile's x is loaded one tile ahead (ds latency hidden)
    const int pbase = (half << 9) + (wid << 4) + col;
    float xn = s_alpha[pbase];
    #pragma unroll 1
    for (int it = 0; it < 8; ++it) {
        const float xc = xn;
        xn = s_alpha[pbase + (((it + 1) & 7) << 6)];   // &7 wrap: last prefetch unused, in-bounds
        const int p = pbase + (it << 6);
        COMPUTE_TILE(xc)
        const float vdir = (grp == 0) ? xp : (grp == 1) ? yp : (grp == 2) ? xpp : ypp;
        const float vmir = (grp == 0) ? (xl2 - xp)
                         : (grp == 1) ? yp
                         : (grp == 2) ? xpp : -ypp;
        out[obase + p] = vdir;
        out[obase + (2048 - p)] = vmir;
    }
}

extern "C" void kernel_launch(void* const* d_in, const int* in_sizes, int n_in,
                              void* d_out, int out_size, void* d_ws, size_t ws_size,
                              hipStream_t stream) {
    const float* alpha = (const float*)d_in[0];
    const float* w0    = (const float*)d_in[1];
    const float* w1    = (const float*)d_in[2];
    const float* w2    = (const float*)d_in[3];
    const float* b0    = (const float*)d_in[4];
    const float* b1    = (const float*)d_in[5];
    const float* b2    = (const float*)d_in[6];
    float* out = (float*)d_out;
    sofa_kernel<<<dim3(N_AB, 2), dim3(256), 0, stream>>>(alpha, w0, w1, w2, b0, b1, b2, out);
}

// Round 8
// 57.880 us; speedup vs baseline: 1.0607x; 1.0607x over previous
//
#include <hip/hip_runtime.h>

#define N_AB  1024
#define NHALF 1025
#define NFULL 2049
#define HDIM  64
#define PLANE ((size_t)N_AB * NFULL)
#define C2L   2.8853900817779268f   // 2*log2(e)
#define TLN2  1.3862943611198906f   // 2*ln(2);  C2L * TLN2 = 4

typedef __bf16 bf16x8 __attribute__((ext_vector_type(8)));
typedef __bf16 bf16x4 __attribute__((ext_vector_type(4)));
typedef float  f32x4  __attribute__((ext_vector_type(4)));
typedef float  f32x2  __attribute__((ext_vector_type(2)));

#define MFMA16(A,B,C) __builtin_amdgcn_mfma_f32_16x16x32_bf16(A,B,C,0,0,0)

// Packed (float2) tanh core: S2 = z*2log2e (pair). H2 = tanh(z), T2 = u-u^2 (1-H^2 = 4T).
#define ACT2(S2,H2,T2) { \
    f32x2 _e; _e.x = __builtin_amdgcn_exp2f(S2.x); _e.y = __builtin_amdgcn_exp2f(S2.y); \
    f32x2 _d = _e + 1.0f; \
    f32x2 _u; _u.x = __builtin_amdgcn_rcpf(_d.x); _u.y = __builtin_amdgcn_rcpf(_d.y); \
    H2 = __builtin_elementwise_fma(_km2, _u, _k1); \
    T2 = __builtin_elementwise_fma(-_u, _u, _u); }

// dual-point layer-1 pair: shared weights (WC2=w0*C2L, BC2=b0*C2L), two x's.
// Two independent ACT2 chains -> scheduler interleaves them (ILP, trans-pipe fill).
#define L1P2(I0, WC2, BC2, BVA, BTA, BVB, BTB) { \
    f32x2 _sA = __builtin_elementwise_fma(WC2, x2A, BC2); \
    f32x2 _sB = __builtin_elementwise_fma(WC2, x2B, BC2); \
    f32x2 _hA, _tA, _hB, _tB; ACT2(_sA,_hA,_tA) ACT2(_sB,_hB,_tB) \
    f32x2 _btA = (_tA * WC2) * TLN2; \
    f32x2 _btB = (_tB * WC2) * TLN2; \
    BVA[I0] = (__bf16)_hA.x;  BVA[I0+1] = (__bf16)_hA.y; \
    BTA[I0] = (__bf16)_btA.x; BTA[I0+1] = (__bf16)_btA.y; \
    BVB[I0] = (__bf16)_hB.x;  BVB[I0+1] = (__bf16)_hB.y; \
    BTB[I0] = (__bf16)_btB.x; BTB[I0+1] = (__bf16)_btB.y; }

// dual-point layer-2 pair: shared B1C2/W2; _dh carries t*dacc; *4 folded into 8.0f later.
#define L2P2(AV2A, AT2A, AV2B, AT2B, B1C2, W20_2, W21_2) { \
    f32x2 _sA = __builtin_elementwise_fma(AV2A, c2l2, B1C2); \
    f32x2 _sB = __builtin_elementwise_fma(AV2B, c2l2, B1C2); \
    f32x2 _hA, _tA, _hB, _tB; ACT2(_sA,_hA,_tA) ACT2(_sB,_hB,_tB) \
    f32x2 _dhA = _tA * (AT2A); \
    f32x2 _dhB = _tB * (AT2B); \
    pv0A = __builtin_elementwise_fma(W20_2, _hA,  pv0A); \
    pv1A = __builtin_elementwise_fma(W21_2, _hA,  pv1A); \
    pt0A = __builtin_elementwise_fma(W20_2, _dhA, pt0A); \
    pt1A = __builtin_elementwise_fma(W21_2, _dhA, pt1A); \
    pv0B = __builtin_elementwise_fma(W20_2, _hB,  pv0B); \
    pv1B = __builtin_elementwise_fma(W21_2, _hB,  pv1B); \
    pt0B = __builtin_elementwise_fma(W20_2, _dhB, pt0B); \
    pt1B = __builtin_elementwise_fma(W21_2, _dhB, pt1B); }

#define L2QUAD2(AVA,ATA,AVB,ATB,B1,WR0,WR1) \
    L2P2(AVA.xy, ATA.xy, AVB.xy, ATB.xy, B1.xy, WR0.xy, WR1.xy) \
    L2P2(AVA.zw, ATA.zw, AVB.zw, ATB.zw, B1.zw, WR0.zw, WR1.zw)

// dual-point tile: 32 points (16 at XA-base, 16 at XB-base); leaves xpA..yppA, xpB..yppB
#define COMPUTE_TILE2(XA, XB) \
    const float xA = (XA), xB = (XB); \
    const f32x2 x2A = {xA, xA}, x2B = {xB, xB}; \
    const float saA = __sinf(xA), caA = __cosf(xA); const float cam1A = caA - 1.0f; \
    const float saB = __sinf(xB), caB = __cosf(xB); const float cam1B = caB - 1.0f; \
    bf16x8 bvA0, bvA1, btA0, btA1, bvB0, bvB1, btB0, btB1; \
    L1P2(0, w0A.xy, b0A.xy, bvA0, btA0, bvB0, btB0) \
    L1P2(2, w0A.zw, b0A.zw, bvA0, btA0, bvB0, btB0) \
    L1P2(4, w0B.xy, b0B.xy, bvA0, btA0, bvB0, btB0) \
    L1P2(6, w0B.zw, b0B.zw, bvA0, btA0, bvB0, btB0) \
    L1P2(0, w0C.xy, b0C.xy, bvA1, btA1, bvB1, btB1) \
    L1P2(2, w0C.zw, b0C.zw, bvA1, btA1, bvB1, btB1) \
    L1P2(4, w0D.xy, b0D.xy, bvA1, btA1, bvB1, btB1) \
    L1P2(6, w0D.zw, b0D.zw, bvA1, btA1, bvB1, btB1) \
    const f32x4 zz = {0.0f,0.0f,0.0f,0.0f}; \
    f32x4 avA0 = MFMA16(A01,bvA1,MFMA16(A00,bvA0,zz)); \
    f32x4 avA1 = MFMA16(A11,bvA1,MFMA16(A10,bvA0,zz)); \
    f32x4 avA2 = MFMA16(A21,bvA1,MFMA16(A20,bvA0,zz)); \
    f32x4 avA3 = MFMA16(A31,bvA1,MFMA16(A30,bvA0,zz)); \
    f32x4 atA0 = MFMA16(A01,btA1,MFMA16(A00,btA0,zz)); \
    f32x4 atA1 = MFMA16(A11,btA1,MFMA16(A10,btA0,zz)); \
    f32x4 atA2 = MFMA16(A21,btA1,MFMA16(A20,btA0,zz)); \
    f32x4 atA3 = MFMA16(A31,btA1,MFMA16(A30,btA0,zz)); \
    f32x4 avB0 = MFMA16(A01,bvB1,MFMA16(A00,bvB0,zz)); \
    f32x4 avB1 = MFMA16(A11,bvB1,MFMA16(A10,bvB0,zz)); \
    f32x4 avB2 = MFMA16(A21,bvB1,MFMA16(A20,bvB0,zz)); \
    f32x4 avB3 = MFMA16(A31,bvB1,MFMA16(A30,bvB0,zz)); \
    f32x4 atB0 = MFMA16(A01,btB1,MFMA16(A00,btB0,zz)); \
    f32x4 atB1 = MFMA16(A11,btB1,MFMA16(A10,btB0,zz)); \
    f32x4 atB2 = MFMA16(A21,btB1,MFMA16(A20,btB0,zz)); \
    f32x4 atB3 = MFMA16(A31,btB1,MFMA16(A30,btB0,zz)); \
    f32x2 pv0A = {0.0f,0.0f}, pv1A = {0.0f,0.0f}, pt0A = {0.0f,0.0f}, pt1A = {0.0f,0.0f}; \
    f32x2 pv0B = {0.0f,0.0f}, pv1B = {0.0f,0.0f}, pt0B = {0.0f,0.0f}, pt1B = {0.0f,0.0f}; \
    L2QUAD2(avA0,atA0,avB0,atB0,b1c0,w2a0,w2b0) \
    L2QUAD2(avA1,atA1,avB1,atB1,b1c1,w2a1,w2b1) \
    L2QUAD2(avA2,atA2,avB2,atB2,b1c2,w2a2,w2b2) \
    L2QUAD2(avA3,atA3,avB3,atB3,b1c3,w2a3,w2b3) \
    float sv0A = pv0A.x + pv0A.y, sv1A = pv1A.x + pv1A.y; \
    float st0A = pt0A.x + pt0A.y, st1A = pt1A.x + pt1A.y; \
    float sv0B = pv0B.x + pv0B.y, sv1B = pv1B.x + pv1B.y; \
    float st0B = pt0B.x + pt0B.y, st1B = pt1B.x + pt1B.y; \
    sv0A += __shfl_xor(sv0A,16); sv0A += __shfl_xor(sv0A,32); \
    sv1A += __shfl_xor(sv1A,16); sv1A += __shfl_xor(sv1A,32); \
    st0A += __shfl_xor(st0A,16); st0A += __shfl_xor(st0A,32); \
    st1A += __shfl_xor(st1A,16); st1A += __shfl_xor(st1A,32); \
    sv0B += __shfl_xor(sv0B,16); sv0B += __shfl_xor(sv0B,32); \
    sv1B += __shfl_xor(sv1B,16); sv1B += __shfl_xor(sv1B,32); \
    st0B += __shfl_xor(st0B,16); st0B += __shfl_xor(st0B,32); \
    st1B += __shfl_xor(st1B,16); st1B += __shfl_xor(st1B,32); \
    const float z0A = sv0A + b20, z1A = sv1A + b21; \
    const float aaA = z0A*z0A, bbA = z1A*z1A; \
    const float daA = 8.0f*z0A*st0A, dbA = 8.0f*z1A*st1A; \
    const float xpA = aaA*cam1A, ypA = bbA*saA; \
    const float xppA = fmaf(daA,cam1A,-(aaA*saA)); \
    const float yppA = fmaf(bbA,caA, dbA*saA); \
    const float z0B = sv0B + b20, z1B = sv1B + b21; \
    const float aaB = z0B*z0B, bbB = z1B*z1B; \
    const float daB = 8.0f*z0B*st0B, dbB = 8.0f*z1B*st1B; \
    const float xpB = aaB*cam1B, ypB = bbB*saB; \
    const float xppB = fmaf(daB,cam1B,-(aaB*saB)); \
    const float yppB = fmaf(bbB,caB, dbB*saB);

__global__ void __launch_bounds__(256, 2) sofa_kernel(   // (256,2): proven no-spill setting
    const float* __restrict__ alpha,
    const float* __restrict__ w0,
    const float* __restrict__ w1,
    const float* __restrict__ w2,
    const float* __restrict__ b0,
    const float* __restrict__ b1,
    const float* __restrict__ b2,
    float* __restrict__ out)
{
    __shared__ __align__(16) __bf16 w1s[HDIM * HDIM];   // XOR-swizzled bf16 W1
    __shared__ float s_alpha[NHALF];
    __shared__ float s_xplast;

    const int n    = blockIdx.x;
    const int tid  = threadIdx.x;
    const int lane = tid & 63;
    const int wid  = tid >> 6;
    const int col  = lane & 15;   // MFMA col (point) / A-row index
    const int grp  = lane >> 4;   // k-slot group / output-plane selector

    const float* __restrict__ w0n = w0 + (size_t)n * HDIM;
    const float* __restrict__ b0n = b0 + (size_t)n * HDIM;
    const float* __restrict__ w1n = w1 + (size_t)n * HDIM * HDIM;
    const float* __restrict__ b1n = b1 + (size_t)n * HDIM;
    const float* __restrict__ w2n = w2 + (size_t)n * 2 * HDIM;
    const float* __restrict__ b2n = b2 + (size_t)n * 2;

    // ---- stage alpha (fp32) and W1 (bf16, 16B-group XOR swizzle) into LDS ----
    for (int e = tid; e < NHALF; e += 256) s_alpha[e] = alpha[e];
    for (int e4 = tid; e4 < (HDIM * HDIM) / 4; e4 += 256) {
        const int i = e4 >> 4, j4 = (e4 & 15) << 2;
        f32x4 v = ((const f32x4*)w1n)[e4];
        bf16x4 b;
        b[0] = (__bf16)v.x; b[1] = (__bf16)v.y; b[2] = (__bf16)v.z; b[3] = (__bf16)v.w;
        *(bf16x4*)&w1s[i * 64 + (((j4 >> 3) ^ (i & 7)) << 3) + (j4 & 7)] = b;
    }
    __syncthreads();

    // ---- constants for packed math ----
    const f32x2 _km2 = {-2.0f, -2.0f};
    const f32x2 _k1  = { 1.0f,  1.0f};
    const f32x2 c2l2 = { C2L,   C2L };

    // ---- per-lane hoisted constants (named ext-vectors -> SSA, no allocas) ----
    const int jb0 = grp * 8, jb1 = 32 + grp * 8;
    f32x4 w0A = *(const f32x4*)(w0n + jb0);
    f32x4 w0B = *(const f32x4*)(w0n + jb0 + 4);
    f32x4 w0C = *(const f32x4*)(w0n + jb1);
    f32x4 w0D = *(const f32x4*)(w0n + jb1 + 4);
    w0A *= C2L; w0B *= C2L; w0C *= C2L; w0D *= C2L;
    f32x4 b0A = *(const f32x4*)(b0n + jb0);
    f32x4 b0B = *(const f32x4*)(b0n + jb0 + 4);
    f32x4 b0C = *(const f32x4*)(b0n + jb1);
    f32x4 b0D = *(const f32x4*)(b0n + jb1 + 4);
    b0A *= C2L; b0B *= C2L; b0C *= C2L; b0D *= C2L;

    f32x4 b1c0 = *(const f32x4*)(b1n + 0  + grp * 4);
    f32x4 b1c1 = *(const f32x4*)(b1n + 16 + grp * 4);
    f32x4 b1c2 = *(const f32x4*)(b1n + 32 + grp * 4);
    f32x4 b1c3 = *(const f32x4*)(b1n + 48 + grp * 4);
    b1c0 *= C2L; b1c1 *= C2L; b1c2 *= C2L; b1c3 *= C2L;

    const f32x4 w2a0 = *(const f32x4*)(w2n + 0  + grp * 4);
    const f32x4 w2a1 = *(const f32x4*)(w2n + 16 + grp * 4);
    const f32x4 w2a2 = *(const f32x4*)(w2n + 32 + grp * 4);
    const f32x4 w2a3 = *(const f32x4*)(w2n + 48 + grp * 4);
    const f32x4 w2b0 = *(const f32x4*)(w2n + 64 + 0  + grp * 4);
    const f32x4 w2b1 = *(const f32x4*)(w2n + 64 + 16 + grp * 4);
    const f32x4 w2b2 = *(const f32x4*)(w2n + 64 + 32 + grp * 4);
    const f32x4 w2b3 = *(const f32x4*)(w2n + 64 + 48 + grp * 4);
    const float b20 = b2n[0], b21 = b2n[1];

    // ---- A-fragments: W1 rows in registers (lane: row=col, k = 32*KH + 8*grp + 0..7) ----
    const bf16x8* w1v = (const bf16x8*)w1s;
    const int sw = col & 7;
#define AF(RT,KH) w1v[((RT)*16 + col)*8 + (((KH)*4 + grp) ^ sw)]
    const bf16x8 A00 = AF(0,0), A01 = AF(0,1), A10 = AF(1,0), A11 = AF(1,1);
    const bf16x8 A20 = AF(2,0), A21 = AF(2,1), A30 = AF(3,0), A31 = AF(3,1);

    const size_t obase = (size_t)grp * PLANE + (size_t)n * NFULL;

    // ---- point 1024 first (wave 0), to get xp_last for the xp mirror ----
    if (wid == 0) {
        COMPUTE_TILE2(s_alpha[1024], s_alpha[1024])
        if (col == 0) {
            out[obase + 1024] = (grp == 0) ? xpA : (grp == 1) ? ypA : (grp == 2) ? xppA : yppA;
            if (grp == 0) s_xplast = xpA;
        }
    }
    __syncthreads();
    const float xl2 = 2.0f * s_xplast;

    // ---- main loop: 8 iters/wave, 32 points each (p and p+512); covers b = 0..1023 ----
    #pragma unroll 1
    for (int it = 0; it < 8; ++it) {
        const int pA = (it << 6) + (wid << 4) + col;
        const int pB = pA + 512;
        COMPUTE_TILE2(s_alpha[pA], s_alpha[pB])
        const float vdirA = (grp == 0) ? xpA : (grp == 1) ? ypA : (grp == 2) ? xppA : yppA;
        const float vmirA = (grp == 0) ? (xl2 - xpA)
                          : (grp == 1) ? ypA
                          : (grp == 2) ? xppA : -yppA;
        const float vdirB = (grp == 0) ? xpB : (grp == 1) ? ypB : (grp == 2) ? xppB : yppB;
        const float vmirB = (grp == 0) ? (xl2 - xpB)
                          : (grp == 1) ? ypB
                          : (grp == 2) ? xppB : -yppB;
        out[obase + pA] = vdirA;
        out[obase + (2048 - pA)] = vmirA;
        out[obase + pB] = vdirB;
        out[obase + (2048 - pB)] = vmirB;
    }
}

extern "C" void kernel_launch(void* const* d_in, const int* in_sizes, int n_in,
                              void* d_out, int out_size, void* d_ws, size_t ws_size,
                              hipStream_t stream) {
    const float* alpha = (const float*)d_in[0];
    const float* w0    = (const float*)d_in[1];
    const float* w1    = (const float*)d_in[2];
    const float* w2    = (const float*)d_in[3];
    const float* b0    = (const float*)d_in[4];
    const float* b1    = (const float*)d_in[5];
    const float* b2    = (const float*)d_in[6];
    float* out = (float*)d_out;
    sofa_kernel<<<dim3(N_AB), dim3(256), 0, stream>>>(alpha, w0, w1, w2, b0, b1, b2, out);
}